// Round 1
// baseline (1680.541 us; speedup 1.0000x reference)
//
#include <hip/hip_runtime.h>

#define N_PTS 32768
#define DIM   512
#define KCODES 4096
#define HW    1024

// ws layout:
// [0, 262144)        best-packed u64 per point (32768 * 8)
// [262144, 278528)   bias f32 per code (4096 * 4)
// [278528, 278532)   sumsq f32

__device__ __forceinline__ unsigned mono(float f) {
    unsigned u = __float_as_uint(f);
    return (u & 0x80000000u) ? ~u : (u | 0x80000000u);
}

__global__ void bias_kernel(const float* __restrict__ E, float* __restrict__ bias) {
    int k = blockIdx.x;
    int l = threadIdx.x; // 64
    const float4* row = (const float4*)(E + (size_t)k * DIM);
    float4 a = row[l * 2];
    float4 b = row[l * 2 + 1];
    float s = a.x * a.x + a.y * a.y + a.z * a.z + a.w * a.w +
              b.x * b.x + b.y * b.y + b.z * b.z + b.w * b.w;
#pragma unroll
    for (int off = 32; off > 0; off >>= 1) s += __shfl_down(s, off, 64);
    if (l == 0) bias[k] = 0.5f * s;
}

// 128(N) x 128(K) tile per block, BD=16 chunks over D=512.
// 256 threads, each an 8x8 microtile over rows {ra..ra+3, ra+64..ra+67},
// cols {cb..cb+3, cb+64..cb+67}  (ra = 4*(t/16), cb = 4*(t%16)).
__global__ __launch_bounds__(256) void score_kernel(
    const float* __restrict__ in, const float* __restrict__ E,
    const float* __restrict__ bias, unsigned long long* __restrict__ best)
{
    __shared__ float As[16][128];
    __shared__ float Bs[16][132]; // +4 pad: conflict-free transposed stores, 16B-aligned rows

    const int t  = threadIdx.x;
    const int k0 = blockIdx.x * 128;
    const int n0 = blockIdx.y * 128;
    const int bb = n0 / HW;       // 128 | 1024, so one batch per tile
    const int hw0 = n0 % HW;
    const float* Abase = in + (size_t)bb * (DIM * HW) + hw0;

    float acc[8][8];
#pragma unroll
    for (int i = 0; i < 8; i++)
#pragma unroll
        for (int j = 0; j < 8; j++) acc[i][j] = 0.f;

    const int ra = (t >> 4) << 2;  // 0..60
    const int cb = (t & 15) << 2;  // 0..60

    for (int d0 = 0; d0 < DIM; d0 += 16) {
        // stage A: As[dd][i] = z[n0+i][d0+dd]  (contiguous in i -> coalesced)
        {
            int dd = t >> 5;          // 0..7
            int i4 = (t & 31) << 2;   // 0..124
            const float* p = Abase + (size_t)(d0 + dd) * HW + i4;
            float4 v0 = *(const float4*)p;
            float4 v1 = *(const float4*)(p + 8 * HW);
            *(float4*)&As[dd][i4]     = v0;
            *(float4*)&As[dd + 8][i4] = v1;
        }
        // stage B transposed: Bs[dd][j] = E[k0+j][d0+dd]
        {
            int j   = t >> 2;         // 0..63
            int dd4 = (t & 3) << 2;   // 0,4,8,12
            const float* p = E + (size_t)(k0 + j) * DIM + d0 + dd4;
            float4 v0 = *(const float4*)p;
            float4 v1 = *(const float4*)(p + (size_t)64 * DIM);
            Bs[dd4 + 0][j] = v0.x; Bs[dd4 + 1][j] = v0.y;
            Bs[dd4 + 2][j] = v0.z; Bs[dd4 + 3][j] = v0.w;
            Bs[dd4 + 0][j + 64] = v1.x; Bs[dd4 + 1][j + 64] = v1.y;
            Bs[dd4 + 2][j + 64] = v1.z; Bs[dd4 + 3][j + 64] = v1.w;
        }
        __syncthreads();
#pragma unroll
        for (int dd = 0; dd < 16; dd++) {
            float4 a0 = *(const float4*)&As[dd][ra];
            float4 a1 = *(const float4*)&As[dd][ra + 64];
            float4 b0 = *(const float4*)&Bs[dd][cb];
            float4 b1 = *(const float4*)&Bs[dd][cb + 64];
            float av[8] = {a0.x, a0.y, a0.z, a0.w, a1.x, a1.y, a1.z, a1.w};
            float bv[8] = {b0.x, b0.y, b0.z, b0.w, b1.x, b1.y, b1.z, b1.w};
#pragma unroll
            for (int i = 0; i < 8; i++)
#pragma unroll
                for (int j = 0; j < 8; j++)
                    acc[i][j] = fmaf(av[i], bv[j], acc[i][j]);
        }
        __syncthreads();
    }

    // epilogue: score = dot - 0.5||e||^2 ; packed argmax (max score, tie -> min k)
    float bcol[8];
#pragma unroll
    for (int j = 0; j < 8; j++) {
        int k = k0 + ((j < 4) ? (cb + j) : (64 + cb + j - 4));
        bcol[j] = bias[k];
    }
    unsigned long long pk[8];
#pragma unroll
    for (int i = 0; i < 8; i++) {
        unsigned long long bestp = 0ull;
#pragma unroll
        for (int j = 0; j < 8; j++) {
            int k = k0 + ((j < 4) ? (cb + j) : (64 + cb + j - 4));
            float s = acc[i][j] - bcol[j];
            unsigned long long p =
                ((unsigned long long)mono(s) << 32) | (unsigned long long)(~(unsigned)k);
            if (p > bestp) bestp = p;
        }
        pk[i] = bestp;
    }
    // reduce across the 16 lanes sharing this row set (lanes g*16..g*16+15)
#pragma unroll
    for (int i = 0; i < 8; i++) {
#pragma unroll
        for (int off = 8; off > 0; off >>= 1) {
            unsigned long long o = __shfl_down(pk[i], off, 16);
            if (o > pk[i]) pk[i] = o;
        }
    }
    if ((t & 15) == 0) {
#pragma unroll
        for (int i = 0; i < 8; i++) {
            int row = n0 + ((i < 4) ? (ra + i) : (64 + ra + i - 4));
            atomicMax(&best[row], pk[i]);
        }
    }
}

__global__ void gather_kernel(const float* __restrict__ in, const float* __restrict__ E,
                              const unsigned long long* __restrict__ best,
                              float* __restrict__ out, float* __restrict__ sumsq)
{
    const int t  = threadIdx.x;
    const int tx = t & 63;
    const int ty = t >> 6;               // 0..3
    const int n  = blockIdx.x * 64 + tx;
    const int bb = n / HW;
    const int hw = n % HW;
    const int k  = (int)(~(unsigned)(best[n] & 0xffffffffull));
    const float* erow = E + (size_t)k * DIM;
    const size_t base = (size_t)bb * (DIM * HW) + hw;
    float local = 0.f;
    for (int d = ty; d < DIM; d += 4) {
        float q = erow[d];
        size_t idx = base + (size_t)d * HW;
        float z = in[idx];
        out[idx] = q;
        float df = z - q;
        local = fmaf(df, df, local);
    }
#pragma unroll
    for (int off = 32; off > 0; off >>= 1) local += __shfl_down(local, off, 64);
    __shared__ float red[4];
    if (tx == 0) red[ty] = local;
    __syncthreads();
    if (t == 0) atomicAdd(sumsq, red[0] + red[1] + red[2] + red[3]);
}

__global__ void finalize_kernel(const float* __restrict__ sumsq, float* __restrict__ out_loss) {
    // e_loss + 0.25*q_loss, both equal mean((z-q)^2) numerically
    *out_loss = 1.25f * (*sumsq) * (1.0f / 16777216.0f);
}

extern "C" void kernel_launch(void* const* d_in, const int* in_sizes, int n_in,
                              void* d_out, int out_size, void* d_ws, size_t ws_size,
                              hipStream_t stream) {
    const float* in = (const float*)d_in[0];   // [32,512,32,32]
    const float* E  = (const float*)d_in[1];   // [4096,512]
    float* out = (float*)d_out;                // 16777216 quantized + 1 loss

    unsigned long long* best = (unsigned long long*)d_ws;
    float* bias  = (float*)((char*)d_ws + 262144);
    float* sumsq = (float*)((char*)d_ws + 278528);

    hipMemsetAsync(d_ws, 0, 278532, stream);

    bias_kernel<<<KCODES, 64, 0, stream>>>(E, bias);

    dim3 grid(KCODES / 128, N_PTS / 128);
    score_kernel<<<grid, 256, 0, stream>>>(in, E, bias, best);

    gather_kernel<<<N_PTS / 64, 256, 0, stream>>>(in, E, best, out, sumsq);

    finalize_kernel<<<1, 1, 0, stream>>>(sumsq, out + 16777216);
}

// Round 2
// 650.365 us; speedup vs baseline: 2.5840x; 2.5840x over previous
//
#include <hip/hip_runtime.h>

#define N_PTS 32768
#define DIM   512
#define KCODES 4096
#define HW    1024
#define MARGIN 0.125f
#define MAXFLAG 2048

typedef _Float16 half8 __attribute__((ext_vector_type(8)));
typedef float f32x4 __attribute__((ext_vector_type(4)));
typedef unsigned long long u64;

// ---- d_out scratch layout (bytes). Gather overwrites all of it at the end.
#define Z16_OFF   0            // f16 [32768][512]  = 32 MB
#define E16_OFF   33554432     // f16 [4096][512]   = 4 MB
#define BIAS_OFF  37748736     // f32 [4096]        = 16 KB
#define TOP2_OFF  37765120     // u64 [32768][4][2] = 2 MB (ends 39862272 < 64 MB)

// ---- ws layout (<= 155656 B, round-1 proved >= 278532 available)
// [0,131072)        k_final i32[32768]
// [131072,139264)   flag list i32[2048]
// [139264,155648)   rescore best u64[2048]
// [155648,155652)   count i32
// [155652,155656)   sumsq f32

__device__ __forceinline__ unsigned mono(float f) {
    unsigned u = __float_as_uint(f);
    return (u & 0x80000000u) ? ~u : (u | 0x80000000u);
}
__device__ __forceinline__ float unmono(unsigned m) {
    unsigned u = (m & 0x80000000u) ? (m & 0x7FFFFFFFu) : ~m;
    return __uint_as_float(u);
}

#define ASYNC16(src, dst) __builtin_amdgcn_global_load_lds( \
    (const __attribute__((address_space(1))) void*)(src), \
    (__attribute__((address_space(3))) void*)(dst), 16, 0, 0)

// ---------------------------------------------------------------- prep E
__global__ void prep_e_kernel(const float* __restrict__ E, _Float16* __restrict__ E16,
                              float* __restrict__ bias) {
    int k = blockIdx.x;
    int l = threadIdx.x; // 64
    const float4* row = (const float4*)(E + (size_t)k * DIM);
    float4 a = row[l * 2];
    float4 b = row[l * 2 + 1];
    half8 h;
    h[0] = (_Float16)a.x; h[1] = (_Float16)a.y; h[2] = (_Float16)a.z; h[3] = (_Float16)a.w;
    h[4] = (_Float16)b.x; h[5] = (_Float16)b.y; h[6] = (_Float16)b.z; h[7] = (_Float16)b.w;
    *(half8*)(E16 + (size_t)k * DIM + l * 8) = h;
    // EXACT same reduction as round-1 bias_kernel (matched numpy)
    float s = a.x * a.x + a.y * a.y + a.z * a.z + a.w * a.w +
              b.x * b.x + b.y * b.y + b.z * b.z + b.w * b.w;
#pragma unroll
    for (int off = 32; off > 0; off >>= 1) s += __shfl_down(s, off, 64);
    if (l == 0) bias[k] = 0.5f * s;
}

// ---------------------------------------------------------------- prep z (NCHW fp32 -> [n][d] f16)
__global__ void prep_z_kernel(const float* __restrict__ in, _Float16* __restrict__ z16) {
    int g = blockIdx.x * 256 + threadIdx.x;   // 65536 threads
    int n = g & 32767;
    int dh = (g >> 15) << 8;                  // 0 or 256
    const float* src = in + (size_t)(n >> 10) * (DIM * HW) + (n & 1023);
    _Float16* dst = z16 + ((size_t)n << 9);
    for (int d0 = dh; d0 < dh + 256; d0 += 8) {
        half8 h;
#pragma unroll
        for (int j = 0; j < 8; j++) h[j] = (_Float16)src[(size_t)(d0 + j) << 10];
        *(half8*)(dst + d0) = h;
    }
}

// ---------------------------------------------------------------- f16 MFMA scorer
// grid (4 ksplit, 256 point-blocks), 256 threads. Block: 128 points x 1024 codes.
// Wave (wc,wp) computes 64 codes x 64 points with 4x4 16x16x32 f16 MFMAs.
// C layout: col(point)=lane&15, row(code)=(lane>>4)*4+reg [m89-verified].
__global__ __launch_bounds__(256) void score16_kernel(
    const _Float16* __restrict__ z16, const _Float16* __restrict__ E16,
    const float* __restrict__ bias, u64* __restrict__ top2)
{
    __shared__ alignas(16) _Float16 A_lds[8][64][8];
    __shared__ alignas(16) _Float16 B_lds[8][64][8];
    __shared__ u64 mbuf[2][128][2];

    const int t = threadIdx.x;
    const int lane = t & 63;
    const int w = t >> 6;
    const int wc = w & 1;
    const int wp = w >> 1;
    const int lm = lane & 15;
    const int lq = lane >> 4;
    const int ks = blockIdx.x;
    const int pt0 = blockIdx.y * 128;

    const u64 PKNEG = ((u64)0x007FFFFFu) << 32;  // pack(-inf)
    u64 b1[4], b2[4];
    float thr2[4];
#pragma unroll
    for (int p = 0; p < 4; p++) { b1[p] = PKNEG; b2[p] = PKNEG; thr2[p] = -INFINITY; }

    for (int ct8 = 0; ct8 < 8; ct8++) {
        const int kb = ks * 1024 + ct8 * 128;
        // init acc with -bias (exact fp32 bias folded into accumulator)
        f32x4 acc[4][4];
#pragma unroll
        for (int ct = 0; ct < 4; ct++) {
            int cbase = kb + 64 * wc + 16 * ct + 4 * lq;
            f32x4 bi;
#pragma unroll
            for (int r = 0; r < 4; r++) bi[r] = -bias[cbase + r];
#pragma unroll
            for (int pt = 0; pt < 4; pt++) acc[ct][pt] = bi;
        }
        for (int dc = 0; dc < 16; dc++) {
            const int d0 = dc * 32;
            // stage in MFMA fragment order: lane -> m/n = lane&15, k-half = lane>>4
#pragma unroll
            for (int i = 0; i < 2; i++) {
                int tile = 2 * w + i;
                ASYNC16(E16 + (size_t)(kb + 16 * tile + lm) * DIM + d0 + 8 * lq,
                        &A_lds[tile][0][0]);
                ASYNC16(z16 + (size_t)(pt0 + 16 * tile + lm) * DIM + d0 + 8 * lq,
                        &B_lds[tile][0][0]);
            }
            __syncthreads();
            half8 aF[4], bF[4];
#pragma unroll
            for (int i = 0; i < 4; i++) aF[i] = *(const half8*)&A_lds[4 * wc + i][lane][0];
#pragma unroll
            for (int i = 0; i < 4; i++) bF[i] = *(const half8*)&B_lds[4 * wp + i][lane][0];
#pragma unroll
            for (int ct = 0; ct < 4; ct++)
#pragma unroll
                for (int pt = 0; pt < 4; pt++)
                    acc[ct][pt] = __builtin_amdgcn_mfma_f32_16x16x32_f16(
                        aF[ct], bF[pt], acc[ct][pt], 0, 0, 0);
            __syncthreads();
        }
        // running top-2 insert (fast path: float threshold + wave-uniform skip)
#pragma unroll
        for (int pt = 0; pt < 4; pt++) {
#pragma unroll
            for (int ct = 0; ct < 4; ct++) {
                f32x4 a = acc[ct][pt];
                bool hit = (a[0] > thr2[pt]) | (a[1] > thr2[pt]) |
                           (a[2] > thr2[pt]) | (a[3] > thr2[pt]);
                if (__any(hit)) {
#pragma unroll
                    for (int r = 0; r < 4; r++) {
                        float v = a[r];
                        if (v > thr2[pt]) {
                            int code = kb + 64 * wc + 16 * ct + 4 * lq + r;
                            u64 pk = ((u64)mono(v) << 32) | (unsigned)(0xFFFu ^ (unsigned)code);
                            if (pk > b1[pt]) { b2[pt] = b1[pt]; b1[pt] = pk; }
                            else if (pk > b2[pt]) { b2[pt] = pk; }
                            thr2[pt] = unmono((unsigned)(b2[pt] >> 32));
                        }
                    }
                }
            }
        }
    }
    // merge the 4 row-groups (lanes l, l+16, l+32, l+48 share a point)
#pragma unroll
    for (int pt = 0; pt < 4; pt++) {
#pragma unroll
        for (int m = 16; m <= 32; m <<= 1) {
            u64 o1 = __shfl_xor(b1[pt], m, 64);
            u64 o2 = __shfl_xor(b2[pt], m, 64);
            u64 m1 = b1[pt] > o1 ? b1[pt] : o1;
            u64 lo = b1[pt] > o1 ? o1 : b1[pt];
            u64 mm = b2[pt] > o2 ? b2[pt] : o2;
            b2[pt] = lo > mm ? lo : mm;
            b1[pt] = m1;
        }
    }
    if (lq == 0) {
#pragma unroll
        for (int pt = 0; pt < 4; pt++) {
            int pib = 64 * wp + 16 * pt + lm;
            mbuf[wc][pib][0] = b1[pt];
            mbuf[wc][pib][1] = b2[pt];
        }
    }
    __syncthreads();
    if (t < 128) {
        u64 x1 = mbuf[0][t][0], x2 = mbuf[0][t][1];
        u64 y1 = mbuf[1][t][0], y2 = mbuf[1][t][1];
        u64 m1 = x1 > y1 ? x1 : y1;
        u64 lo = x1 > y1 ? y1 : x1;
        u64 mm = x2 > y2 ? x2 : y2;
        u64 m2 = lo > mm ? lo : mm;
        size_t gpt = (size_t)(pt0 + t);
        top2[gpt * 8 + ks * 2]     = m1;
        top2[gpt * 8 + ks * 2 + 1] = m2;
    }
}

// ---------------------------------------------------------------- merge k-splits, flag
__global__ void merge_kernel(const u64* __restrict__ top2, int* __restrict__ k_final,
                             int* __restrict__ list, int* __restrict__ count) {
    int pt = blockIdx.x * 256 + threadIdx.x;
    const u64* p = top2 + (size_t)pt * 8;
    u64 B1 = 0, B2 = 0;
#pragma unroll
    for (int ks = 0; ks < 4; ks++) {
        u64 p1 = p[ks * 2], p2 = p[ks * 2 + 1];
        u64 m1 = B1 > p1 ? B1 : p1;
        u64 lo = B1 > p1 ? p1 : B1;
        u64 mm = B2 > p2 ? B2 : p2;
        B2 = lo > mm ? lo : mm;
        B1 = m1;
    }
    k_final[pt] = 0xFFF ^ (int)(B1 & 0xFFFull);
    float s1 = unmono((unsigned)(B1 >> 32));
    float s2 = unmono((unsigned)(B2 >> 32));
    if (s1 - s2 < MARGIN) {
        int idx = atomicAdd(count, 1);
        if (idx < MAXFLAG) list[idx] = pt;
    }
}

// ---------------------------------------------------------------- exact fp32 rescore (round-1 GEMM on flagged rows)
__global__ __launch_bounds__(256) void rescore_kernel(
    const float* __restrict__ in, const float* __restrict__ E,
    const float* __restrict__ bias, const int* __restrict__ list,
    const int* __restrict__ count, u64* __restrict__ rb)
{
    __shared__ float As[16][128];
    __shared__ float Bs[16][132];
    __shared__ int pl[128];

    int cnt = *count; if (cnt > MAXFLAG) cnt = MAXFLAG;
    const int t  = threadIdx.x;
    const int k0 = blockIdx.x * 128;
    const int r0 = blockIdx.y * 128;
    if (r0 >= cnt) return;
    if (t < 128) {
        int idx = r0 + t; if (idx >= cnt) idx = cnt - 1;
        pl[t] = list[idx];
    }
    __syncthreads();

    float acc[8][8];
#pragma unroll
    for (int i = 0; i < 8; i++)
#pragma unroll
        for (int j = 0; j < 8; j++) acc[i][j] = 0.f;

    const int ra = (t >> 4) << 2;
    const int cb = (t & 15) << 2;

    for (int d0 = 0; d0 < DIM; d0 += 16) {
        {
            int dd = t >> 5;
            int i4 = (t & 31) << 2;
#pragma unroll
            for (int u = 0; u < 4; u++) {
                int pt = pl[i4 + u];
                const float* base = in + (size_t)(pt >> 10) * (DIM * HW) + (pt & 1023);
                As[dd][i4 + u]     = base[(size_t)(d0 + dd) << 10];
                As[dd + 8][i4 + u] = base[(size_t)(d0 + dd + 8) << 10];
            }
        }
        {
            int j   = t >> 2;
            int dd4 = (t & 3) << 2;
            const float* p = E + (size_t)(k0 + j) * DIM + d0 + dd4;
            float4 v0 = *(const float4*)p;
            float4 v1 = *(const float4*)(p + (size_t)64 * DIM);
            Bs[dd4 + 0][j] = v0.x; Bs[dd4 + 1][j] = v0.y;
            Bs[dd4 + 2][j] = v0.z; Bs[dd4 + 3][j] = v0.w;
            Bs[dd4 + 0][j + 64] = v1.x; Bs[dd4 + 1][j + 64] = v1.y;
            Bs[dd4 + 2][j + 64] = v1.z; Bs[dd4 + 3][j + 64] = v1.w;
        }
        __syncthreads();
#pragma unroll
        for (int dd = 0; dd < 16; dd++) {
            float4 a0 = *(const float4*)&As[dd][ra];
            float4 a1 = *(const float4*)&As[dd][ra + 64];
            float4 b0 = *(const float4*)&Bs[dd][cb];
            float4 b1v = *(const float4*)&Bs[dd][cb + 64];
            float av[8] = {a0.x, a0.y, a0.z, a0.w, a1.x, a1.y, a1.z, a1.w};
            float bv[8] = {b0.x, b0.y, b0.z, b0.w, b1v.x, b1v.y, b1v.z, b1v.w};
#pragma unroll
            for (int i = 0; i < 8; i++)
#pragma unroll
                for (int j = 0; j < 8; j++)
                    acc[i][j] = fmaf(av[i], bv[j], acc[i][j]);
        }
        __syncthreads();
    }

    float bcol[8];
#pragma unroll
    for (int j = 0; j < 8; j++) {
        int k = k0 + ((j < 4) ? (cb + j) : (64 + cb + j - 4));
        bcol[j] = bias[k];
    }
    u64 pk[8];
#pragma unroll
    for (int i = 0; i < 8; i++) {
        u64 bestp = 0ull;
#pragma unroll
        for (int j = 0; j < 8; j++) {
            int k = k0 + ((j < 4) ? (cb + j) : (64 + cb + j - 4));
            float s = acc[i][j] - bcol[j];
            u64 p = ((u64)mono(s) << 32) | (u64)(~(unsigned)k);
            if (p > bestp) bestp = p;
        }
        pk[i] = bestp;
    }
#pragma unroll
    for (int i = 0; i < 8; i++) {
#pragma unroll
        for (int off = 8; off > 0; off >>= 1) {
            u64 o = __shfl_down(pk[i], off, 16);
            if (o > pk[i]) pk[i] = o;
        }
    }
    if ((t & 15) == 0) {
#pragma unroll
        for (int i = 0; i < 8; i++) {
            int row = r0 + ((i < 4) ? (ra + i) : (64 + ra + i - 4));
            int slot = row < cnt ? row : cnt - 1;
            atomicMax(&rb[slot], pk[i]);
        }
    }
}

__global__ void apply_kernel(const int* __restrict__ list, const int* __restrict__ count,
                             const u64* __restrict__ rb, int* __restrict__ k_final) {
    int i = blockIdx.x * 256 + threadIdx.x;
    int cnt = *count; if (cnt > MAXFLAG) cnt = MAXFLAG;
    if (i < cnt) k_final[list[i]] = (int)(~(unsigned)(rb[i] & 0xffffffffull));
}

// ---------------------------------------------------------------- gather + loss
__global__ void gather_kernel(const float* __restrict__ in, const float* __restrict__ E,
                              const int* __restrict__ k_final,
                              float* __restrict__ out, float* __restrict__ sumsq)
{
    const int t  = threadIdx.x;
    const int tx = t & 63;
    const int ty = t >> 6;
    const int n  = blockIdx.x * 64 + tx;
    const int k  = k_final[n];
    const float* erow = E + (size_t)k * DIM;
    const size_t base = (size_t)(n >> 10) * (DIM * HW) + (n & 1023);
    float local = 0.f;
    for (int d = ty; d < DIM; d += 4) {
        float q = erow[d];
        size_t idx = base + ((size_t)d << 10);
        float z = in[idx];
        out[idx] = q;
        float df = z - q;
        local = fmaf(df, df, local);
    }
#pragma unroll
    for (int off = 32; off > 0; off >>= 1) local += __shfl_down(local, off, 64);
    __shared__ float red[4];
    if (tx == 0) red[ty] = local;
    __syncthreads();
    if (t == 0) atomicAdd(sumsq, red[0] + red[1] + red[2] + red[3]);
}

__global__ void finalize_kernel(const float* __restrict__ sumsq, float* __restrict__ out_loss) {
    *out_loss = 1.25f * (*sumsq) * (1.0f / 16777216.0f);
}

// ----------------------------------------------------------------
extern "C" void kernel_launch(void* const* d_in, const int* in_sizes, int n_in,
                              void* d_out, int out_size, void* d_ws, size_t ws_size,
                              hipStream_t stream) {
    const float* in = (const float*)d_in[0];
    const float* E  = (const float*)d_in[1];
    float* out = (float*)d_out;
    char* ob = (char*)d_out;

    _Float16* z16 = (_Float16*)(ob + Z16_OFF);
    _Float16* E16 = (_Float16*)(ob + E16_OFF);
    float* bias   = (float*)(ob + BIAS_OFF);
    u64* top2     = (u64*)(ob + TOP2_OFF);

    int* k_final = (int*)d_ws;
    int* list    = (int*)((char*)d_ws + 131072);
    u64* rb      = (u64*)((char*)d_ws + 139264);
    int* count   = (int*)((char*)d_ws + 155648);
    float* sumsq = (float*)((char*)d_ws + 155652);

    hipMemsetAsync(d_ws, 0, 155656, stream);

    prep_e_kernel<<<KCODES, 64, 0, stream>>>(E, E16, bias);
    prep_z_kernel<<<256, 256, 0, stream>>>(in, z16);

    score16_kernel<<<dim3(4, 256), 256, 0, stream>>>(z16, E16, bias, top2);

    merge_kernel<<<128, 256, 0, stream>>>(top2, k_final, list, count);

    rescore_kernel<<<dim3(32, 16), 256, 0, stream>>>(in, E, bias, list, count, rb);
    apply_kernel<<<8, 256, 0, stream>>>(list, count, rb, k_final);

    gather_kernel<<<N_PTS / 64, 256, 0, stream>>>(in, E, k_final, out, sumsq);
    finalize_kernel<<<1, 1, 0, stream>>>(sumsq, out + 16777216);
}

// Round 3
// 523.367 us; speedup vs baseline: 3.2110x; 1.2427x over previous
//
#include <hip/hip_runtime.h>

#define N_PTS 32768
#define DIM   512
#define KCODES 4096
#define HW    1024
#define MARGIN 0.125f
#define MAXFLAG 2048

typedef _Float16 half8 __attribute__((ext_vector_type(8)));
typedef float f32x4 __attribute__((ext_vector_type(4)));
typedef unsigned long long u64;

// ---- d_out scratch layout (bytes). gather overwrites everything at the end.
#define E16_OFF   0            // f16 [4096][512]    = 4 MB
#define BIAS_OFF  4194304      // f32 [4096]         = 16 KB
#define TOP2_OFF  4210688      // u64 [32768][2ks][2]= 1 MB   (ends 5259264)
#define ZC_OFF    5259264      // f32 [2048][512]    = 4 MB   (ends 9453568 < 64 MB)

// ---- ws layout (<= 155656 B, proven available)
// [0,131072)        k_final i32[32768]
// [131072,139264)   flag list i32[2048]
// [139264,155648)   rescore best u64[2048]
// [155648,155652)   count i32
// [155652,155656)   sumsq f32

__device__ __forceinline__ unsigned mono(float f) {
    unsigned u = __float_as_uint(f);
    return (u & 0x80000000u) ? ~u : (u | 0x80000000u);
}
__device__ __forceinline__ float unmono(unsigned m) {
    unsigned u = (m & 0x80000000u) ? (m & 0x7FFFFFFFu) : ~m;
    return __uint_as_float(u);
}

#define ASYNC16(src, dst) __builtin_amdgcn_global_load_lds( \
    (const __attribute__((address_space(1))) void*)(src), \
    (__attribute__((address_space(3))) void*)(dst), 16, 0, 0)

// ---------------------------------------------------------------- prep E (f16 convert + bias)
__global__ void prep_e_kernel(const float* __restrict__ E, _Float16* __restrict__ E16,
                              float* __restrict__ bias) {
    int k = blockIdx.x;
    int l = threadIdx.x; // 64
    const float4* row = (const float4*)(E + (size_t)k * DIM);
    float4 a = row[l * 2];
    float4 b = row[l * 2 + 1];
    half8 h;
    h[0] = (_Float16)a.x; h[1] = (_Float16)a.y; h[2] = (_Float16)a.z; h[3] = (_Float16)a.w;
    h[4] = (_Float16)b.x; h[5] = (_Float16)b.y; h[6] = (_Float16)b.z; h[7] = (_Float16)b.w;
    *(half8*)(E16 + (size_t)k * DIM + l * 8) = h;
    float s = a.x * a.x + a.y * a.y + a.z * a.z + a.w * a.w +
              b.x * b.x + b.y * b.y + b.z * b.z + b.w * b.w;
#pragma unroll
    for (int off = 32; off > 0; off >>= 1) s += __shfl_down(s, off, 64);
    if (l == 0) bias[k] = 0.5f * s;
}

// ---------------------------------------------------------------- z-register-resident f16 MFMA scorer
// grid (2 ksplit, 256 pt-blocks) x 256 threads. Block: 128 pts x 2048 codes.
// Wave w owns 32 pts (2 tiles of 16), full D=512 in registers (zf[2][16] half8).
// Phase = 32 codes: stage E-tile 32KB in LDS (lane-order frag layout, R2-proven),
// 64 MFMAs/wave per barrier pair. C layout: col(pt)=lane&15, row(code)=(lane>>4)*4+reg.
__global__ __launch_bounds__(256, 2) void score16_kernel(
    const float* __restrict__ in, const _Float16* __restrict__ E16,
    const float* __restrict__ bias, u64* __restrict__ top2)
{
    // slot s = kc*128 + ct*64 + lane; each slot = 8 halfs (16 B). 32 KB total.
    __shared__ alignas(16) _Float16 stage[2048 * 8];

    const int t    = threadIdx.x;
    const int lane = t & 63;
    const int w    = t >> 6;     // 0..3
    const int lm   = lane & 15;
    const int lq   = lane >> 4;  // 0..3
    const int ks   = blockIdx.x; // 0..1
    const int pt0  = blockIdx.y * 128;

    // ---- preload z fragments for this wave's 32 points (fp32 NCHW -> f16, RTN)
    half8 zf[2][16];
#pragma unroll
    for (int pt = 0; pt < 2; pt++) {
        const int n = pt0 + 32 * w + 16 * pt + lm;
        const float* zb = in + (size_t)(n >> 10) * (DIM * HW) + (n & 1023);
#pragma unroll
        for (int kc = 0; kc < 16; kc++) {
            const int d0 = kc * 32 + lq * 8;
            half8 h;
#pragma unroll
            for (int j = 0; j < 8; j++) h[j] = (_Float16)zb[(size_t)(d0 + j) << 10];
            zf[pt][kc] = h;
        }
    }

    const u64 PKNEG = ((u64)0x007FFFFFu) << 32;  // pack(-inf)
    u64 b1[2], b2[2];
    float thr2[2];
#pragma unroll
    for (int p = 0; p < 2; p++) { b1[p] = PKNEG; b2[p] = PKNEG; thr2[p] = -INFINITY; }

    for (int f = 0; f < 64; f++) {
        const int code0 = ks * 2048 + f * 32;
        // ---- stage E-tile: issue 8 ASYNC16 per thread
#pragma unroll
        for (int i = 0; i < 8; i++) {
            const int kc = 4 * w + (i >> 1);
            const int ct = i & 1;
            const _Float16* src = E16 + (size_t)(code0 + ct * 16 + lm) * DIM + kc * 32 + lq * 8;
            ASYNC16(src, stage + ((size_t)(w * 512 + i * 64) << 3));
        }
        __syncthreads();
        // ---- acc init with exact fp32 -bias
        f32x4 acc[2][2];
#pragma unroll
        for (int ct = 0; ct < 2; ct++) {
            const float4 bv = *(const float4*)&bias[code0 + ct * 16 + lq * 4];
            f32x4 bi; bi[0] = -bv.x; bi[1] = -bv.y; bi[2] = -bv.z; bi[3] = -bv.w;
            acc[ct][0] = bi; acc[ct][1] = bi;
        }
        // ---- 64 MFMAs from LDS A-frags x register z-frags
#pragma unroll
        for (int kc = 0; kc < 16; kc++) {
            half8 a0 = *(const half8*)&stage[(size_t)(kc * 128 + lane) << 3];
            half8 a1 = *(const half8*)&stage[(size_t)(kc * 128 + 64 + lane) << 3];
            acc[0][0] = __builtin_amdgcn_mfma_f32_16x16x32_f16(a0, zf[0][kc], acc[0][0], 0, 0, 0);
            acc[0][1] = __builtin_amdgcn_mfma_f32_16x16x32_f16(a0, zf[1][kc], acc[0][1], 0, 0, 0);
            acc[1][0] = __builtin_amdgcn_mfma_f32_16x16x32_f16(a1, zf[0][kc], acc[1][0], 0, 0, 0);
            acc[1][1] = __builtin_amdgcn_mfma_f32_16x16x32_f16(a1, zf[1][kc], acc[1][1], 0, 0, 0);
        }
        __syncthreads();
        // ---- running top-2 insert (threshold fast path)
#pragma unroll
        for (int pt = 0; pt < 2; pt++) {
#pragma unroll
            for (int ct = 0; ct < 2; ct++) {
                f32x4 a = acc[ct][pt];
                bool hit = (a[0] > thr2[pt]) | (a[1] > thr2[pt]) |
                           (a[2] > thr2[pt]) | (a[3] > thr2[pt]);
                if (__any(hit)) {
#pragma unroll
                    for (int r = 0; r < 4; r++) {
                        float v = a[r];
                        if (v > thr2[pt]) {
                            int code = code0 + ct * 16 + lq * 4 + r;
                            u64 pk = ((u64)mono(v) << 32) | (unsigned)(0xFFFu ^ (unsigned)code);
                            if (pk > b1[pt]) { b2[pt] = b1[pt]; b1[pt] = pk; }
                            else if (pk > b2[pt]) { b2[pt] = pk; }
                            thr2[pt] = unmono((unsigned)(b2[pt] >> 32));
                        }
                    }
                }
            }
        }
    }
    // ---- merge across lq groups (lanes lm, lm+16, lm+32, lm+48 share a point)
#pragma unroll
    for (int pt = 0; pt < 2; pt++) {
#pragma unroll
        for (int m = 16; m <= 32; m <<= 1) {
            u64 o1 = __shfl_xor(b1[pt], m, 64);
            u64 o2 = __shfl_xor(b2[pt], m, 64);
            u64 m1 = b1[pt] > o1 ? b1[pt] : o1;
            u64 lo = b1[pt] > o1 ? o1 : b1[pt];
            u64 mm = b2[pt] > o2 ? b2[pt] : o2;
            b2[pt] = lo > mm ? lo : mm;
            b1[pt] = m1;
        }
    }
    if (lq == 0) {
#pragma unroll
        for (int pt = 0; pt < 2; pt++) {
            const size_t p = (size_t)(pt0 + 32 * w + 16 * pt + lm);
            top2[p * 4 + ks * 2]     = b1[pt];
            top2[p * 4 + ks * 2 + 1] = b2[pt];
        }
    }
}

// ---------------------------------------------------------------- merge 2 k-splits, flag
__global__ void merge_kernel(const u64* __restrict__ top2, int* __restrict__ k_final,
                             int* __restrict__ list, int* __restrict__ count) {
    int pt = blockIdx.x * 256 + threadIdx.x;
    const u64* p = top2 + (size_t)pt * 4;
    u64 B1 = 0, B2 = 0;
#pragma unroll
    for (int ks = 0; ks < 2; ks++) {
        u64 p1 = p[ks * 2], p2 = p[ks * 2 + 1];
        u64 m1 = B1 > p1 ? B1 : p1;
        u64 lo = B1 > p1 ? p1 : B1;
        u64 mm = B2 > p2 ? B2 : p2;
        B2 = lo > mm ? lo : mm;
        B1 = m1;
    }
    k_final[pt] = 0xFFF ^ (int)(B1 & 0xFFFull);
    float s1 = unmono((unsigned)(B1 >> 32));
    float s2 = unmono((unsigned)(B2 >> 32));
    if (s1 - s2 < MARGIN) {
        int idx = atomicAdd(count, 1);
        if (idx < MAXFLAG) list[idx] = pt;
    }
}

// ---------------------------------------------------------------- compact flagged z columns -> zc[cnt][512] fp32
__global__ void compact_kernel(const float* __restrict__ in, const int* __restrict__ list,
                               const int* __restrict__ count, float* __restrict__ zc) {
    int cnt = *count; if (cnt > MAXFLAG) cnt = MAXFLAG;
    const int w = threadIdx.x >> 6;
    const int l = threadIdx.x & 63;
    const int i = blockIdx.x * 4 + w;
    if (i >= cnt) return;
    const int pt = list[i];
    const float* zb = in + (size_t)(pt >> 10) * (DIM * HW) + (pt & 1023);
    float v[8];
#pragma unroll
    for (int j = 0; j < 8; j++) v[j] = zb[(size_t)(l * 8 + j) << 10];
    float4* dst = (float4*)(zc + (size_t)i * DIM + l * 8);
    dst[0] = make_float4(v[0], v[1], v[2], v[3]);
    dst[1] = make_float4(v[4], v[5], v[6], v[7]);
}

// ---------------------------------------------------------------- exact fp32 rescore (coalesced zc reads)
__global__ __launch_bounds__(256) void rescore_kernel(
    const float* __restrict__ zc, const float* __restrict__ E,
    const float* __restrict__ bias, const int* __restrict__ count,
    u64* __restrict__ rb)
{
    __shared__ float As[16][128];
    __shared__ float Bs[16][132];

    int cnt = *count; if (cnt > MAXFLAG) cnt = MAXFLAG;
    const int t  = threadIdx.x;
    const int k0 = blockIdx.x * 128;
    const int r0 = blockIdx.y * 128;
    if (r0 >= cnt) return;

    float acc[8][8];
#pragma unroll
    for (int i = 0; i < 8; i++)
#pragma unroll
        for (int j = 0; j < 8; j++) acc[i][j] = 0.f;

    const int ra = (t >> 4) << 2;
    const int cb = (t & 15) << 2;

    for (int d0 = 0; d0 < DIM; d0 += 16) {
        {
            int j   = t >> 2;
            int dd4 = (t & 3) << 2;
            int rA = r0 + j;        if (rA >= cnt) rA = cnt - 1;
            int rB = r0 + j + 64;   if (rB >= cnt) rB = cnt - 1;
            float4 v0 = *(const float4*)&zc[(size_t)rA * DIM + d0 + dd4];
            float4 v1 = *(const float4*)&zc[(size_t)rB * DIM + d0 + dd4];
            As[dd4 + 0][j] = v0.x; As[dd4 + 1][j] = v0.y;
            As[dd4 + 2][j] = v0.z; As[dd4 + 3][j] = v0.w;
            As[dd4 + 0][j + 64] = v1.x; As[dd4 + 1][j + 64] = v1.y;
            As[dd4 + 2][j + 64] = v1.z; As[dd4 + 3][j + 64] = v1.w;
        }
        {
            int j   = t >> 2;
            int dd4 = (t & 3) << 2;
            const float* p = E + (size_t)(k0 + j) * DIM + d0 + dd4;
            float4 v0 = *(const float4*)p;
            float4 v1 = *(const float4*)(p + (size_t)64 * DIM);
            Bs[dd4 + 0][j] = v0.x; Bs[dd4 + 1][j] = v0.y;
            Bs[dd4 + 2][j] = v0.z; Bs[dd4 + 3][j] = v0.w;
            Bs[dd4 + 0][j + 64] = v1.x; Bs[dd4 + 1][j + 64] = v1.y;
            Bs[dd4 + 2][j + 64] = v1.z; Bs[dd4 + 3][j + 64] = v1.w;
        }
        __syncthreads();
#pragma unroll
        for (int dd = 0; dd < 16; dd++) {
            float4 a0 = *(const float4*)&As[dd][ra];
            float4 a1 = *(const float4*)&As[dd][ra + 64];
            float4 b0 = *(const float4*)&Bs[dd][cb];
            float4 b1v = *(const float4*)&Bs[dd][cb + 64];
            float av[8] = {a0.x, a0.y, a0.z, a0.w, a1.x, a1.y, a1.z, a1.w};
            float bv[8] = {b0.x, b0.y, b0.z, b0.w, b1v.x, b1v.y, b1v.z, b1v.w};
#pragma unroll
            for (int i = 0; i < 8; i++)
#pragma unroll
                for (int j = 0; j < 8; j++)
                    acc[i][j] = fmaf(av[i], bv[j], acc[i][j]);
        }
        __syncthreads();
    }

    float bcol[8];
#pragma unroll
    for (int j = 0; j < 8; j++) {
        int k = k0 + ((j < 4) ? (cb + j) : (64 + cb + j - 4));
        bcol[j] = bias[k];
    }
    u64 pk[8];
#pragma unroll
    for (int i = 0; i < 8; i++) {
        u64 bestp = 0ull;
#pragma unroll
        for (int j = 0; j < 8; j++) {
            int k = k0 + ((j < 4) ? (cb + j) : (64 + cb + j - 4));
            float s = acc[i][j] - bcol[j];
            u64 p = ((u64)mono(s) << 32) | (u64)(~(unsigned)k);
            if (p > bestp) bestp = p;
        }
        pk[i] = bestp;
    }
#pragma unroll
    for (int i = 0; i < 8; i++) {
#pragma unroll
        for (int off = 8; off > 0; off >>= 1) {
            u64 o = __shfl_down(pk[i], off, 16);
            if (o > pk[i]) pk[i] = o;
        }
    }
    if ((t & 15) == 0) {
#pragma unroll
        for (int i = 0; i < 8; i++) {
            int row = r0 + ((i < 4) ? (ra + i) : (64 + ra + i - 4));
            int slot = row < cnt ? row : cnt - 1;
            atomicMax(&rb[slot], pk[i]);
        }
    }
}

__global__ void apply_kernel(const int* __restrict__ list, const int* __restrict__ count,
                             const u64* __restrict__ rb, int* __restrict__ k_final) {
    int i = blockIdx.x * 256 + threadIdx.x;
    int cnt = *count; if (cnt > MAXFLAG) cnt = MAXFLAG;
    if (i < cnt) k_final[list[i]] = (int)(~(unsigned)(rb[i] & 0xffffffffull));
}

// ---------------------------------------------------------------- gather + loss
__global__ void gather_kernel(const float* __restrict__ in, const float* __restrict__ E,
                              const int* __restrict__ k_final,
                              float* __restrict__ out, float* __restrict__ sumsq)
{
    const int t  = threadIdx.x;
    const int tx = t & 63;
    const int ty = t >> 6;
    const int n  = blockIdx.x * 64 + tx;
    const int k  = k_final[n];
    const float* erow = E + (size_t)k * DIM;
    const size_t base = (size_t)(n >> 10) * (DIM * HW) + (n & 1023);
    float local = 0.f;
    for (int d = ty; d < DIM; d += 4) {
        float q = erow[d];
        size_t idx = base + ((size_t)d << 10);
        float z = in[idx];
        out[idx] = q;
        float df = z - q;
        local = fmaf(df, df, local);
    }
#pragma unroll
    for (int off = 32; off > 0; off >>= 1) local += __shfl_down(local, off, 64);
    __shared__ float red[4];
    if (tx == 0) red[ty] = local;
    __syncthreads();
    if (t == 0) atomicAdd(sumsq, red[0] + red[1] + red[2] + red[3]);
}

__global__ void finalize_kernel(const float* __restrict__ sumsq, float* __restrict__ out_loss) {
    *out_loss = 1.25f * (*sumsq) * (1.0f / 16777216.0f);
}

// ----------------------------------------------------------------
extern "C" void kernel_launch(void* const* d_in, const int* in_sizes, int n_in,
                              void* d_out, int out_size, void* d_ws, size_t ws_size,
                              hipStream_t stream) {
    const float* in = (const float*)d_in[0];
    const float* E  = (const float*)d_in[1];
    float* out = (float*)d_out;
    char* ob = (char*)d_out;

    _Float16* E16 = (_Float16*)(ob + E16_OFF);
    float* bias   = (float*)(ob + BIAS_OFF);
    u64* top2     = (u64*)(ob + TOP2_OFF);
    float* zc     = (float*)(ob + ZC_OFF);

    int* k_final = (int*)d_ws;
    int* list    = (int*)((char*)d_ws + 131072);
    u64* rb      = (u64*)((char*)d_ws + 139264);
    int* count   = (int*)((char*)d_ws + 155648);
    float* sumsq = (float*)((char*)d_ws + 155652);

    hipMemsetAsync(d_ws, 0, 155656, stream);

    prep_e_kernel<<<KCODES, 64, 0, stream>>>(E, E16, bias);

    score16_kernel<<<dim3(2, 256), 256, 0, stream>>>(in, E16, bias, top2);

    merge_kernel<<<128, 256, 0, stream>>>(top2, k_final, list, count);

    compact_kernel<<<512, 256, 0, stream>>>(in, list, count, zc);
    rescore_kernel<<<dim3(32, 16), 256, 0, stream>>>(zc, E, bias, count, rb);
    apply_kernel<<<8, 256, 0, stream>>>(list, count, rb, k_final);

    gather_kernel<<<N_PTS / 64, 256, 0, stream>>>(in, E, k_final, out, sumsq);
    finalize_kernel<<<1, 1, 0, stream>>>(sumsq, out + 16777216);
}

// Round 4
// 504.442 us; speedup vs baseline: 3.3315x; 1.0375x over previous
//
#include <hip/hip_runtime.h>

#define N_PTS 32768
#define DIM   512
#define KCODES 4096
#define HW    1024
#define MARGIN 0.125f
#define MAXFLAG 2048

typedef _Float16 half8 __attribute__((ext_vector_type(8)));
typedef float f32x4 __attribute__((ext_vector_type(4)));
typedef unsigned long long u64;

// ---- d_out scratch layout (bytes). gather overwrites everything at the end.
#define E16_OFF   0            // f16 [4096][512]    = 4 MB
#define BIAS_OFF  4194304      // f32 [4096]         = 16 KB
#define TOP2_OFF  4210688      // u64 [32768][2ks][2]= 1 MB   (ends 5259264)
#define ZC_OFF    5259264      // f32 [2048][512]    = 4 MB   (ends 9453568 < 64 MB)

// ---- ws layout: zeroed region first (memset only [0,16392))
// [0,16384)         rescore best u64[2048]
// [16384,16388)     count i32
// [16388,16392)     sumsq f32
// [16392,24584)     flag list i32[2048]
// [24584,155656)    k_final i32[32768]

__device__ __forceinline__ unsigned mono(float f) {
    unsigned u = __float_as_uint(f);
    return (u & 0x80000000u) ? ~u : (u | 0x80000000u);
}
__device__ __forceinline__ float unmono(unsigned m) {
    unsigned u = (m & 0x80000000u) ? (m & 0x7FFFFFFFu) : ~m;
    return __uint_as_float(u);
}

#define ASYNC16(src, dst) __builtin_amdgcn_global_load_lds( \
    (const __attribute__((address_space(1))) void*)(src), \
    (__attribute__((address_space(3))) void*)(dst), 16, 0, 0)

// ---------------------------------------------------------------- prep E (f16 convert + bias)
__global__ void prep_e_kernel(const float* __restrict__ E, _Float16* __restrict__ E16,
                              float* __restrict__ bias) {
    int k = blockIdx.x;
    int l = threadIdx.x; // 64
    const float4* row = (const float4*)(E + (size_t)k * DIM);
    float4 a = row[l * 2];
    float4 b = row[l * 2 + 1];
    half8 h;
    h[0] = (_Float16)a.x; h[1] = (_Float16)a.y; h[2] = (_Float16)a.z; h[3] = (_Float16)a.w;
    h[4] = (_Float16)b.x; h[5] = (_Float16)b.y; h[6] = (_Float16)b.z; h[7] = (_Float16)b.w;
    *(half8*)(E16 + (size_t)k * DIM + l * 8) = h;
    float s = a.x * a.x + a.y * a.y + a.z * a.z + a.w * a.w +
              b.x * b.x + b.y * b.y + b.z * b.z + b.w * b.w;
#pragma unroll
    for (int off = 32; off > 0; off >>= 1) s += __shfl_down(s, off, 64);
    if (l == 0) bias[k] = 0.5f * s;
}

// ---------------------------------------------------------------- z-register-resident, E double-buffered scorer
// grid (2 ksplit, 256 pt-blocks) x 256 threads. Block: 128 pts x 2048 codes.
// Wave w owns 32 pts (2 tiles of 16), full D=512 in registers (zf[2][16] half8).
// Phase = 32 codes staged in LDS buf[f&1]; loads for f+1 issued right after the
// single barrier, so vmcnt(0) drain at the NEXT barrier covers loads that had a
// whole phase to land. Math identical to R3 (proven absmax 0).
__global__ __launch_bounds__(256, 2) void score16_kernel(
    const float* __restrict__ in, const _Float16* __restrict__ E16,
    const float* __restrict__ bias, u64* __restrict__ top2)
{
    // slot s = kc*128 + ct*64 + lane; each slot = 8 halfs (16 B). 32 KB per buffer.
    __shared__ alignas(16) _Float16 stage[2][2048 * 8];

    const int t    = threadIdx.x;
    const int lane = t & 63;
    const int w    = t >> 6;     // 0..3
    const int lm   = lane & 15;
    const int lq   = lane >> 4;  // 0..3
    const int ks   = blockIdx.x; // 0..1
    const int pt0  = blockIdx.y * 128;

    // ---- preload z fragments for this wave's 32 points (fp32 NCHW -> f16, RTN)
    half8 zf[2][16];
#pragma unroll
    for (int pt = 0; pt < 2; pt++) {
        const int n = pt0 + 32 * w + 16 * pt + lm;
        const float* zb = in + (size_t)(n >> 10) * (DIM * HW) + (n & 1023);
#pragma unroll
        for (int kc = 0; kc < 16; kc++) {
            const int d0 = kc * 32 + lq * 8;
            half8 h;
#pragma unroll
            for (int j = 0; j < 8; j++) h[j] = (_Float16)zb[(size_t)(d0 + j) << 10];
            zf[pt][kc] = h;
        }
    }

    const u64 PKNEG = ((u64)0x007FFFFFu) << 32;  // pack(-inf)
    u64 b1[2], b2[2];
    float thr2[2];
#pragma unroll
    for (int p = 0; p < 2; p++) { b1[p] = PKNEG; b2[p] = PKNEG; thr2[p] = -INFINITY; }

    // prologue: stage phase 0 into buf 0
    {
        const int code0 = ks * 2048;
#pragma unroll
        for (int i = 0; i < 8; i++) {
            const int kc = 4 * w + (i >> 1);
            const int ct = i & 1;
            ASYNC16(E16 + (size_t)(code0 + ct * 16 + lm) * DIM + kc * 32 + lq * 8,
                    &stage[0][(size_t)(w * 512 + i * 64) << 3]);
        }
    }

    for (int f = 0; f < 64; f++) {
        const int code0 = ks * 2048 + f * 32;
        const int buf = f & 1;
        __syncthreads();   // drains vmcnt(0): buf[f&1] ready; gates reuse of buf[(f+1)&1]
        // ---- issue loads for phase f+1 (wraps harmlessly at f=63)
        {
            const int cn = ks * 2048 + ((f + 1) & 63) * 32;
#pragma unroll
            for (int i = 0; i < 8; i++) {
                const int kc = 4 * w + (i >> 1);
                const int ct = i & 1;
                ASYNC16(E16 + (size_t)(cn + ct * 16 + lm) * DIM + kc * 32 + lq * 8,
                        &stage[buf ^ 1][(size_t)(w * 512 + i * 64) << 3]);
            }
        }
        // ---- acc init with exact fp32 -bias
        f32x4 acc[2][2];
#pragma unroll
        for (int ct = 0; ct < 2; ct++) {
            const float4 bv = *(const float4*)&bias[code0 + ct * 16 + lq * 4];
            f32x4 bi; bi[0] = -bv.x; bi[1] = -bv.y; bi[2] = -bv.z; bi[3] = -bv.w;
            acc[ct][0] = bi; acc[ct][1] = bi;
        }
        // ---- 64 MFMAs from LDS A-frags x register z-frags
#pragma unroll
        for (int kc = 0; kc < 16; kc++) {
            half8 a0 = *(const half8*)&stage[buf][(size_t)(kc * 128 + lane) << 3];
            half8 a1 = *(const half8*)&stage[buf][(size_t)(kc * 128 + 64 + lane) << 3];
            acc[0][0] = __builtin_amdgcn_mfma_f32_16x16x32_f16(a0, zf[0][kc], acc[0][0], 0, 0, 0);
            acc[0][1] = __builtin_amdgcn_mfma_f32_16x16x32_f16(a0, zf[1][kc], acc[0][1], 0, 0, 0);
            acc[1][0] = __builtin_amdgcn_mfma_f32_16x16x32_f16(a1, zf[0][kc], acc[1][0], 0, 0, 0);
            acc[1][1] = __builtin_amdgcn_mfma_f32_16x16x32_f16(a1, zf[1][kc], acc[1][1], 0, 0, 0);
        }
        // ---- running top-2 insert (threshold fast path)
#pragma unroll
        for (int pt = 0; pt < 2; pt++) {
#pragma unroll
            for (int ct = 0; ct < 2; ct++) {
                f32x4 a = acc[ct][pt];
                bool hit = (a[0] > thr2[pt]) | (a[1] > thr2[pt]) |
                           (a[2] > thr2[pt]) | (a[3] > thr2[pt]);
                if (__any(hit)) {
#pragma unroll
                    for (int r = 0; r < 4; r++) {
                        float v = a[r];
                        if (v > thr2[pt]) {
                            int code = code0 + ct * 16 + lq * 4 + r;
                            u64 pk = ((u64)mono(v) << 32) | (unsigned)(0xFFFu ^ (unsigned)code);
                            if (pk > b1[pt]) { b2[pt] = b1[pt]; b1[pt] = pk; }
                            else if (pk > b2[pt]) { b2[pt] = pk; }
                            thr2[pt] = unmono((unsigned)(b2[pt] >> 32));
                        }
                    }
                }
            }
        }
    }
    // ---- merge across lq groups (lanes lm, lm+16, lm+32, lm+48 share a point)
#pragma unroll
    for (int pt = 0; pt < 2; pt++) {
#pragma unroll
        for (int m = 16; m <= 32; m <<= 1) {
            u64 o1 = __shfl_xor(b1[pt], m, 64);
            u64 o2 = __shfl_xor(b2[pt], m, 64);
            u64 m1 = b1[pt] > o1 ? b1[pt] : o1;
            u64 lo = b1[pt] > o1 ? o1 : b1[pt];
            u64 mm = b2[pt] > o2 ? b2[pt] : o2;
            b2[pt] = lo > mm ? lo : mm;
            b1[pt] = m1;
        }
    }
    if (lq == 0) {
#pragma unroll
        for (int pt = 0; pt < 2; pt++) {
            const size_t p = (size_t)(pt0 + 32 * w + 16 * pt + lm);
            top2[p * 4 + ks * 2]     = b1[pt];
            top2[p * 4 + ks * 2 + 1] = b2[pt];
        }
    }
}

// ---------------------------------------------------------------- merge 2 k-splits + flag + compact z row
__global__ void merge_compact_kernel(const u64* __restrict__ top2, const float* __restrict__ in,
                                     int* __restrict__ k_final, int* __restrict__ list,
                                     int* __restrict__ count, float* __restrict__ zc) {
    int pt = blockIdx.x * 256 + threadIdx.x;
    const u64* p = top2 + (size_t)pt * 4;
    u64 B1 = 0, B2 = 0;
#pragma unroll
    for (int ks = 0; ks < 2; ks++) {
        u64 p1 = p[ks * 2], p2 = p[ks * 2 + 1];
        u64 m1 = B1 > p1 ? B1 : p1;
        u64 lo = B1 > p1 ? p1 : B1;
        u64 mm = B2 > p2 ? B2 : p2;
        B2 = lo > mm ? lo : mm;
        B1 = m1;
    }
    k_final[pt] = 0xFFF ^ (int)(B1 & 0xFFFull);
    float s1 = unmono((unsigned)(B1 >> 32));
    float s2 = unmono((unsigned)(B2 >> 32));
    if (s1 - s2 < MARGIN) {
        int idx = atomicAdd(count, 1);
        if (idx < MAXFLAG) {
            list[idx] = pt;
            const float* zb = in + (size_t)(pt >> 10) * (DIM * HW) + (pt & 1023);
            float* dst = zc + (size_t)idx * DIM;
#pragma unroll 8
            for (int d = 0; d < DIM; d++) dst[d] = zb[(size_t)d << 10];
        }
    }
}

// ---------------------------------------------------------------- exact fp32 rescore (coalesced zc reads)
__global__ __launch_bounds__(256) void rescore_kernel(
    const float* __restrict__ zc, const float* __restrict__ E,
    const float* __restrict__ bias, const int* __restrict__ count,
    u64* __restrict__ rb)
{
    __shared__ float As[16][128];
    __shared__ float Bs[16][132];

    int cnt = *count; if (cnt > MAXFLAG) cnt = MAXFLAG;
    const int t  = threadIdx.x;
    const int k0 = blockIdx.x * 128;
    const int r0 = blockIdx.y * 128;
    if (r0 >= cnt) return;

    float acc[8][8];
#pragma unroll
    for (int i = 0; i < 8; i++)
#pragma unroll
        for (int j = 0; j < 8; j++) acc[i][j] = 0.f;

    const int ra = (t >> 4) << 2;
    const int cb = (t & 15) << 2;

    for (int d0 = 0; d0 < DIM; d0 += 16) {
        {
            int j   = t >> 2;
            int dd4 = (t & 3) << 2;
            int rA = r0 + j;        if (rA >= cnt) rA = cnt - 1;
            int rB = r0 + j + 64;   if (rB >= cnt) rB = cnt - 1;
            float4 v0 = *(const float4*)&zc[(size_t)rA * DIM + d0 + dd4];
            float4 v1 = *(const float4*)&zc[(size_t)rB * DIM + d0 + dd4];
            As[dd4 + 0][j] = v0.x; As[dd4 + 1][j] = v0.y;
            As[dd4 + 2][j] = v0.z; As[dd4 + 3][j] = v0.w;
            As[dd4 + 0][j + 64] = v1.x; As[dd4 + 1][j + 64] = v1.y;
            As[dd4 + 2][j + 64] = v1.z; As[dd4 + 3][j + 64] = v1.w;
        }
        {
            int j   = t >> 2;
            int dd4 = (t & 3) << 2;
            const float* p = E + (size_t)(k0 + j) * DIM + d0 + dd4;
            float4 v0 = *(const float4*)p;
            float4 v1 = *(const float4*)(p + (size_t)64 * DIM);
            Bs[dd4 + 0][j] = v0.x; Bs[dd4 + 1][j] = v0.y;
            Bs[dd4 + 2][j] = v0.z; Bs[dd4 + 3][j] = v0.w;
            Bs[dd4 + 0][j + 64] = v1.x; Bs[dd4 + 1][j + 64] = v1.y;
            Bs[dd4 + 2][j + 64] = v1.z; Bs[dd4 + 3][j + 64] = v1.w;
        }
        __syncthreads();
#pragma unroll
        for (int dd = 0; dd < 16; dd++) {
            float4 a0 = *(const float4*)&As[dd][ra];
            float4 a1 = *(const float4*)&As[dd][ra + 64];
            float4 b0 = *(const float4*)&Bs[dd][cb];
            float4 b1v = *(const float4*)&Bs[dd][cb + 64];
            float av[8] = {a0.x, a0.y, a0.z, a0.w, a1.x, a1.y, a1.z, a1.w};
            float bv[8] = {b0.x, b0.y, b0.z, b0.w, b1v.x, b1v.y, b1v.z, b1v.w};
#pragma unroll
            for (int i = 0; i < 8; i++)
#pragma unroll
                for (int j = 0; j < 8; j++)
                    acc[i][j] = fmaf(av[i], bv[j], acc[i][j]);
        }
        __syncthreads();
    }

    float bcol[8];
#pragma unroll
    for (int j = 0; j < 8; j++) {
        int k = k0 + ((j < 4) ? (cb + j) : (64 + cb + j - 4));
        bcol[j] = bias[k];
    }
    u64 pk[8];
#pragma unroll
    for (int i = 0; i < 8; i++) {
        u64 bestp = 0ull;
#pragma unroll
        for (int j = 0; j < 8; j++) {
            int k = k0 + ((j < 4) ? (cb + j) : (64 + cb + j - 4));
            float s = acc[i][j] - bcol[j];
            u64 p = ((u64)mono(s) << 32) | (u64)(~(unsigned)k);
            if (p > bestp) bestp = p;
        }
        pk[i] = bestp;
    }
#pragma unroll
    for (int i = 0; i < 8; i++) {
#pragma unroll
        for (int off = 8; off > 0; off >>= 1) {
            u64 o = __shfl_down(pk[i], off, 16);
            if (o > pk[i]) pk[i] = o;
        }
    }
    if ((t & 15) == 0) {
#pragma unroll
        for (int i = 0; i < 8; i++) {
            int row = r0 + ((i < 4) ? (ra + i) : (64 + ra + i - 4));
            int slot = row < cnt ? row : cnt - 1;
            atomicMax(&rb[slot], pk[i]);
        }
    }
}

__global__ void apply_kernel(const int* __restrict__ list, const int* __restrict__ count,
                             const u64* __restrict__ rb, int* __restrict__ k_final) {
    int i = blockIdx.x * 256 + threadIdx.x;
    int cnt = *count; if (cnt > MAXFLAG) cnt = MAXFLAG;
    if (i < cnt) k_final[list[i]] = (int)(~(unsigned)(rb[i] & 0xffffffffull));
}

// ---------------------------------------------------------------- gather + loss
__global__ void gather_kernel(const float* __restrict__ in, const float* __restrict__ E,
                              const int* __restrict__ k_final,
                              float* __restrict__ out, float* __restrict__ sumsq)
{
    const int t  = threadIdx.x;
    const int tx = t & 63;
    const int ty = t >> 6;
    const int n  = blockIdx.x * 64 + tx;
    const int k  = k_final[n];
    const float* erow = E + (size_t)k * DIM;
    const size_t base = (size_t)(n >> 10) * (DIM * HW) + (n & 1023);
    float local = 0.f;
    for (int d = ty; d < DIM; d += 4) {
        float q = erow[d];
        size_t idx = base + ((size_t)d << 10);
        float z = in[idx];
        out[idx] = q;
        float df = z - q;
        local = fmaf(df, df, local);
    }
#pragma unroll
    for (int off = 32; off > 0; off >>= 1) local += __shfl_down(local, off, 64);
    __shared__ float red[4];
    if (tx == 0) red[ty] = local;
    __syncthreads();
    if (t == 0) atomicAdd(sumsq, red[0] + red[1] + red[2] + red[3]);
}

__global__ void finalize_kernel(const float* __restrict__ sumsq, float* __restrict__ out_loss) {
    *out_loss = 1.25f * (*sumsq) * (1.0f / 16777216.0f);
}

// ----------------------------------------------------------------
extern "C" void kernel_launch(void* const* d_in, const int* in_sizes, int n_in,
                              void* d_out, int out_size, void* d_ws, size_t ws_size,
                              hipStream_t stream) {
    const float* in = (const float*)d_in[0];
    const float* E  = (const float*)d_in[1];
    float* out = (float*)d_out;
    char* ob = (char*)d_out;

    _Float16* E16 = (_Float16*)(ob + E16_OFF);
    float* bias   = (float*)(ob + BIAS_OFF);
    u64* top2     = (u64*)(ob + TOP2_OFF);
    float* zc     = (float*)(ob + ZC_OFF);

    u64* rb      = (u64*)d_ws;
    int* count   = (int*)((char*)d_ws + 16384);
    float* sumsq = (float*)((char*)d_ws + 16388);
    int* list    = (int*)((char*)d_ws + 16392);
    int* k_final = (int*)((char*)d_ws + 24584);

    hipMemsetAsync(d_ws, 0, 16392, stream);

    prep_e_kernel<<<KCODES, 64, 0, stream>>>(E, E16, bias);

    score16_kernel<<<dim3(2, 256), 256, 0, stream>>>(in, E16, bias, top2);

    merge_compact_kernel<<<128, 256, 0, stream>>>(top2, in, k_final, list, count, zc);

    rescore_kernel<<<dim3(32, 16), 256, 0, stream>>>(zc, E, bias, count, rb);
    apply_kernel<<<8, 256, 0, stream>>>(list, count, rb, k_final);

    gather_kernel<<<N_PTS / 64, 256, 0, stream>>>(in, E, k_final, out, sumsq);
    finalize_kernel<<<1, 1, 0, stream>>>(sumsq, out + 16777216);
}